// Round 14
// baseline (112.636 us; speedup 1.0000x reference)
//
#include <hip/hip_runtime.h>
#include <cstdint>

#define CN (384*1024)          // 393216
#define BCN (16*CN)            // 6291456
#define EPS 1e-5f

typedef float f32x2 __attribute__((ext_vector_type(2)));
typedef float f32x4 __attribute__((ext_vector_type(4)));

// workspace layout (bytes)
#define WPT_OFF   0u           // f32[384][384] = 589824
#define WQB_OFF   589824u      // bf16-as-u16[385][384] (row 384 = zeros), ends 885504
#define QINV_OFF  1179648u
#define QOFF_OFF  (QINV_OFF + 1536u)
#define PINV_OFF  (QINV_OFF + 3072u)
#define POFF_OFF  (QINV_OFF + 4608u)
#define C0_OFF    (QINV_OFF + 6144u)
#define LCNT2_OFF 1187840u     // u8[1024 blocks][64 units], ends 1253376
#define XM_OFF    1310720u     // u64[4][16][16][384] n-packed spikes, ends 4456448
#define XMT_OFF   4456448u     // u64[4][16][1024][6] c-packed spikes, ends 7602176
#define LISTS2_OFF 7602176u    // u16[1024][64][24] offsets (idx*3), ends ~10748032
#define MST_OFF   XM_OFF       // masked q-spikes u64[col][6]; reuses xm (dead after k1bc)

// ---------------- K0: transposes (wp->f32 wpT, wq->bf16 wqb + zero row) + consts ----
__global__ __launch_bounds__(256) void k0_prep(const float* __restrict__ wq,
                                               const float* __restrict__ wp,
                                               const float* __restrict__ qg,
                                               const float* __restrict__ qb,
                                               const float* __restrict__ qm,
                                               const float* __restrict__ qv,
                                               const float* __restrict__ pg,
                                               const float* __restrict__ pb,
                                               const float* __restrict__ pm,
                                               const float* __restrict__ pv,
                                               const float* __restrict__ bp,
                                               char* __restrict__ ws) {
    int bid = blockIdx.x;
    if (bid < 576) {
        int i = bid * 256 + threadIdx.x;             // 0..147455
        int c = i / 384, o = i % 384;
        ((float*)(ws + WPT_OFF))[c * 384 + o] = wp[o * 384 + c];
    } else if (bid < 1154) {
        int j = (bid - 576) * 256 + threadIdx.x;     // 0..147967
        if (j >= 147840) return;                     // 385*384
        int r = j / 384, o = j % 384;
        unsigned short v = 0;
        if (r < 384) {
            unsigned u = __float_as_uint(wq[o * 384 + r]);
            v = (unsigned short)((u + 0x7fffu + ((u >> 16) & 1u)) >> 16);  // rne bf16
        }
        ((unsigned short*)(ws + WQB_OFF))[j] = v;
    } else {
        for (int i = threadIdx.x; i < 384; i += 256) {
            float qi = qg[i] / sqrtf(qv[i] + EPS);
            ((float*)(ws + QINV_OFF))[i] = qi;
            ((float*)(ws + QOFF_OFF))[i] = qb[i] - qm[i] * qi;
            float pi = pg[i] / sqrtf(pv[i] + EPS);
            float po = pb[i] - pm[i] * pi;
            ((float*)(ws + PINV_OFF))[i] = pi;
            ((float*)(ws + POFF_OFF))[i] = po;
            ((float*)(ws + C0_OFF))[i] = bp[i] * pi + po;  // output when GEMM2 input == 0
        }
    }
}

// ---------------- K1: shortcut LIF -> n-packed spike bitmasks ----------------
__global__ __launch_bounds__(256) void k1_lif(const float* __restrict__ x,
                                              unsigned long long* __restrict__ xm) {
    int wid  = (blockIdx.x * 256 + threadIdx.x) >> 6;   // 0..98303
    int lane = threadIdx.x & 63;
    int c = wid % 384;
    int g = (wid / 384) & 15;
    int b = wid / (384 * 16);
    const float* xp = x + (size_t)b * CN + (size_t)c * 1024 + g * 64 + lane;
    float v = 0.f;
    #pragma unroll
    for (int t = 0; t < 4; ++t) {
        float xv = xp[(size_t)t * BCN];
        float h = v + (xv - v) * 0.5f;                  // v + (x - v)/tau, tau = 2
        bool s = (h >= 1.0f);
        unsigned long long m = __ballot(s);
        v = s ? 0.f : h;
        if (lane == 0) xm[(((size_t)t * 16 + b) * 16 + g) * 384 + c] = m;
    }
}

// ---------------- K1bc: fused bit-transpose + offset-list build --------------------
// wave = (t,b,g). 6 x {load 64 row-words, 64 ballots} -> lane n holds its column's
// 6 c-packed words in registers; writes xmT (fallback path) and builds the padded
// u16 offset list + lcnt directly (no intermediate global round-trip).
__global__ __launch_bounds__(256) void k1bc(const unsigned long long* __restrict__ xm,
                                            unsigned long long* __restrict__ xmT,
                                            unsigned short* __restrict__ lists2,
                                            unsigned char* __restrict__ lcnt2) {
    int wid  = (blockIdx.x * 256 + threadIdx.x) >> 6;   // 0..1023 = tb*16+g
    int lane = threadIdx.x & 63;
    int g  = wid & 15;
    int tb = wid >> 4;                                  // t*16 + b
    unsigned long long T[6];
    #pragma unroll
    for (int cg = 0; cg < 6; ++cg) {
        unsigned long long W = xm[((size_t)tb * 16 + g) * 384 + cg * 64 + lane];
        unsigned long long colw = 0ull;
        #pragma unroll
        for (int k = 0; k < 64; ++k) {
            unsigned long long bk = __ballot((W >> k) & 1ull);
            if (lane == k) colw = bk;
        }
        T[cg] = colw;
    }
    const int n   = g * 64 + lane;
    const size_t col = ((size_t)tb << 10) + n;
    #pragma unroll
    for (int cg = 0; cg < 6; ++cg) xmT[col * 6 + cg] = T[cg];
    const int blockid = (tb & 15) * 64 + (n >> 4);      // b*64 + n/16
    const int un = (lane & 15) * 4 + (tb >> 4);         // (n%16)*4 + t
    unsigned short* lp = lists2 + ((size_t)blockid * 64 + un) * 24;
    int k = 0;
    #pragma unroll
    for (int cg = 0; cg < 6; ++cg) {
        unsigned long long m = T[cg];
        while (m) {
            int j = __builtin_ctzll(m);
            m &= m - 1;
            if (k < 24) lp[k] = (unsigned short)((cg * 64 + j) * 3);
            ++k;
        }
    }
    int kk = k > 24 ? 24 : k;
    for (int i = kk; i < 24; ++i) lp[i] = 1152;         // 384*3 -> zero row (always pad)
    lcnt2[(size_t)blockid * 64 + un] =
        (k > 24) ? 0xFF : (unsigned char)((k + 7) >> 3);
}

// ---------------- K2: wave-per-row gather GEMM1 + BN + LIF + mask + OUTPUT WRITE ---
// block = (b, nt16), 512 threads = 8 waves; wave w owns n-locals {2w, 2w+1}.
// One dwordx3 loads a whole 768B bf16 row (lane owns o = lane*6+e). After the
// gather, the block writes out[t,b,:,16n] = c0[o] for every t whose 16 columns are
// all spike-free (always, on this input) -- the 100MB write hides in gather latency.
// Tile = 384 o x 16 n floats = 1536 float4 units = 3 x 512 threads.
// Any t with a nonzero column is skipped here; k3's slow path rewrites that g-tile.
#define BLO(w) __uint_as_float((w) << 16)
#define BHI(w) __uint_as_float((w) & 0xFFFF0000u)
#define PK(w)  ((f32x2){BLO(w), BHI(w)})
#define RL(v, l) ((unsigned)__builtin_amdgcn_readlane((int)(v), (l)))

#define GROW8(W0, W1, W2, W3) do {                                                \
    uint3 d0_ = *(const uint3*)(wqc + ((size_t)((W0) & 0xffffu) << 8) + voff);    \
    uint3 d1_ = *(const uint3*)(wqc + ((size_t)((W0) >> 16) << 8) + voff);        \
    uint3 d2_ = *(const uint3*)(wqc + ((size_t)((W1) & 0xffffu) << 8) + voff);    \
    uint3 d3_ = *(const uint3*)(wqc + ((size_t)((W1) >> 16) << 8) + voff);        \
    uint3 d4_ = *(const uint3*)(wqc + ((size_t)((W2) & 0xffffu) << 8) + voff);    \
    uint3 d5_ = *(const uint3*)(wqc + ((size_t)((W2) >> 16) << 8) + voff);        \
    uint3 d6_ = *(const uint3*)(wqc + ((size_t)((W3) & 0xffffu) << 8) + voff);    \
    uint3 d7_ = *(const uint3*)(wqc + ((size_t)((W3) >> 16) << 8) + voff);        \
    s0 += ((PK(d0_.x) + PK(d1_.x)) + (PK(d2_.x) + PK(d3_.x)))                     \
        + ((PK(d4_.x) + PK(d5_.x)) + (PK(d6_.x) + PK(d7_.x)));                    \
    s1 += ((PK(d0_.y) + PK(d1_.y)) + (PK(d2_.y) + PK(d3_.y)))                     \
        + ((PK(d4_.y) + PK(d5_.y)) + (PK(d6_.y) + PK(d7_.y)));                    \
    s2 += ((PK(d0_.z) + PK(d1_.z)) + (PK(d2_.z) + PK(d3_.z)))                     \
        + ((PK(d4_.z) + PK(d5_.z)) + (PK(d6_.z) + PK(d7_.z)));                    \
} while (0)

__global__ __launch_bounds__(512, 2) void k2_qpath(const char* __restrict__ wqc,
                                                   const float* __restrict__ qinv_,
                                                   const float* __restrict__ qoff_,
                                                   const unsigned short* __restrict__ lists2,
                                                   const unsigned char* __restrict__ lcnt2,
                                                   const unsigned long long* __restrict__ xmT,
                                                   const unsigned char* __restrict__ ak,
                                                   const unsigned char* __restrict__ av,
                                                   const float* __restrict__ c0,
                                                   unsigned long long* __restrict__ msT,
                                                   float* __restrict__ out) {
    __shared__ __align__(4) unsigned char zflag[16];    // bit t: column (t,nl) has spikes
    const int tid  = threadIdx.x;
    const int lane = tid & 63;
    const int w    = tid >> 6;                   // wave 0..7
    const int nt   = blockIdx.x & 63;
    const int b    = blockIdx.x >> 6;
    const int voff = lane * 12;                  // 12B per lane: o = lane*6 + e

    float qi[6], qo[6];
    #pragma unroll
    for (int e = 0; e < 6; ++e) {
        qi[e] = qinv_[lane * 6 + e];
        qo[e] = qoff_[lane * 6 + e];
    }
    // lane-cache the block's gather metadata: lane u holds unit u's 24 u16 offsets
    const char* lb = (const char*)lists2 + (size_t)blockIdx.x * 3072 + lane * 48;
    const uint4 L0 = *(const uint4*)lb;           // slots 0-7
    const uint4 L1 = *(const uint4*)(lb + 16);    // slots 8-15
    const uint4 L2 = *(const uint4*)(lb + 32);    // slots 16-23
    const unsigned lcv = *(const unsigned*)((const char*)lcnt2
                          + (size_t)blockIdx.x * 64 + (lane & 15) * 4);

    #pragma unroll
    for (int i = 0; i < 2; ++i) {
        const int nl = w * 2 + i;                // n-local 0..15 (wave-uniform)
        const int n  = nt * 16 + nl;
        const unsigned lcw = RL(lcv, nl);        // 4 round-counts (one per t)
        f32x2 a0[4], a1[4], a2[4];
        // ---- phase 1: fixed 16 slots per t (compiler-scheduled batches) ----
        #pragma unroll
        for (int t = 0; t < 4; ++t) {
            const int un = nl * 4 + t;           // wave-uniform unit index
            const unsigned Wa = RL(L0.x, un), Wb = RL(L0.y, un);
            const unsigned Wc = RL(L0.z, un), Wd = RL(L0.w, un);
            const unsigned We = RL(L1.x, un), Wf = RL(L1.y, un);
            const unsigned Wg = RL(L1.z, un), Wh = RL(L1.w, un);
            f32x2 s0 = {0.f, 0.f}, s1 = {0.f, 0.f}, s2 = {0.f, 0.f};
            GROW8(Wa, Wb, Wc, Wd);
            GROW8(We, Wf, Wg, Wh);
            a0[t] = s0; a1[t] = s1; a2[t] = s2;
        }
        // ---- phase 2: rare third round (k = 17..24) ----
        #pragma unroll
        for (int t = 0; t < 4; ++t) {
            if (((lcw >> (8 * t)) & 0xffu) == 3u) {
                const int un = nl * 4 + t;
                const unsigned Wa = RL(L2.x, un), Wb = RL(L2.y, un);
                const unsigned Wc = RL(L2.z, un), Wd = RL(L2.w, un);
                f32x2 s0 = a0[t], s1 = a1[t], s2 = a2[t];
                GROW8(Wa, Wb, Wc, Wd);
                a0[t] = s0; a1[t] = s1; a2[t] = s2;
            }
        }
        // ---- phase 3: overflow fallback (k > 24, ~never), recompute from zero ----
        #pragma unroll
        for (int t = 0; t < 4; ++t) {
            if (((lcw >> (8 * t)) & 0xffu) == 0xffu) {
                const int col = ((t * 16 + b) << 10) + n;
                const unsigned long long* mp = xmT + (size_t)col * 6;
                f32x2 s0 = {0.f, 0.f}, s1 = {0.f, 0.f}, s2 = {0.f, 0.f};
                #pragma unroll
                for (int cg = 0; cg < 6; ++cg) {
                    unsigned long long mm = mp[cg];
                    while (mm) {
                        int j = __builtin_ctzll(mm);
                        mm &= mm - 1;
                        uint3 dd = *(const uint3*)(wqc + (size_t)(cg * 64 + j) * 768 + voff);
                        s0 += PK(dd.x); s1 += PK(dd.y); s2 += PK(dd.z);
                    }
                }
                a0[t] = s0; a1[t] = s1; a2[t] = s2;
            }
        }
        // ---- BN + LIF + attn-mask epilogue (6 owned o's per lane) ----
        float v[6] = {0.f, 0.f, 0.f, 0.f, 0.f, 0.f};
        unsigned nzb = 0;
        #pragma unroll
        for (int t = 0; t < 4; ++t) {
            const int col = ((t * 16 + b) << 10) + n;
            const float val[6] = {a0[t].x, a0[t].y, a1[t].x, a1[t].y, a2[t].x, a2[t].y};
            bool sp[6];
            #pragma unroll
            for (int e = 0; e < 6; ++e) {
                float q = val[e] * qi[e] + qo[e];
                float h = 0.5f * (v[e] + q);     // v + (q - v)/2
                bool s = (h >= 1.0f);
                v[e] = s ? 0.f : h;
                if (s) {                          // rare: attn lookup only on q-spike
                    size_t ix = ((size_t)((t * 16 + b) * 384 + lane * 6 + e) << 10) + n;
                    s = (ak[ix] != 0) && (av[ix] != 0);
                }
                sp[e] = s;
            }
            unsigned long long B0 = __ballot(sp[0]);
            unsigned long long B1 = __ballot(sp[1]);
            unsigned long long B2 = __ballot(sp[2]);
            unsigned long long B3 = __ballot(sp[3]);
            unsigned long long B4 = __ballot(sp[4]);
            unsigned long long B5 = __ballot(sp[5]);
            nzb |= (((B0 | B1 | B2 | B3 | B4 | B5) != 0ull) ? 1u : 0u) << t;
            // word e: bit l -> o = l*6 + e
            unsigned long long sel = lane == 0 ? B0 : lane == 1 ? B1 : lane == 2 ? B2
                                   : lane == 3 ? B3 : lane == 4 ? B4 : B5;
            if (lane < 6) msT[(size_t)col * 6 + lane] = sel;
        }
        if (lane == 0) zflag[nl] = (unsigned char)nzb;
    }
    // ---- fused output write: all-zero t-slices get out = c0[o] (nontemporal) ----
    // this block's tile: 384 o x 16 n floats = 1536 float4 units = 3 x 512 threads
    __syncthreads();
    const unsigned z0 = ((const unsigned*)zflag)[0];
    const unsigned z1 = ((const unsigned*)zflag)[1];
    const unsigned z2 = ((const unsigned*)zflag)[2];
    const unsigned z3 = ((const unsigned*)zflag)[3];
    const unsigned zall = z0 | z1 | z2 | z3;
    float cv[3];
    #pragma unroll
    for (int k = 0; k < 3; ++k) cv[k] = c0[(tid + k * 512) >> 2];
    #pragma unroll
    for (int t = 0; t < 4; ++t) {
        if (((zall >> t) & 0x01010101u) == 0u) {        // all 16 columns spike-free
            f32x4* base4 = (f32x4*)out + (size_t)(t * 16 + b) * 384 * 256 + nt * 4;
            #pragma unroll
            for (int k = 0; k < 3; ++k) {
                int i2 = tid + k * 512;                 // 0..1535
                int o = i2 >> 2, n4 = i2 & 3;           // o in [0,384), n4 in [0,4)
                float vv = cv[k];
                __builtin_nontemporal_store((f32x4){vv, vv, vv, vv},
                                            base4 + (size_t)o * 256 + n4);
            }
        }
        // else: some column spikes -> k3's slow path rewrites the whole g-tile
    }
}

// ---------------- K3: slow-path guard (gather GEMM2 only where spikes exist) -------
__global__ __launch_bounds__(384) void k3_proj(const float* __restrict__ wpT,
                                               const float* __restrict__ pinv_,
                                               const float* __restrict__ poff_,
                                               const float* __restrict__ bp,
                                               const unsigned long long* __restrict__ msT,
                                               float* __restrict__ out) {
    __shared__ unsigned int wflag[6];
    const int tid = threadIdx.x;
    const int bid = blockIdx.x;
    const int g = bid & 15, b = (bid >> 4) & 15, t = bid >> 8;
    const unsigned long long* mbase = msT + ((size_t)(t * 16 + b) * 1024 + g * 64) * 6;
    unsigned long long m = mbase[tid];           // 384 words: n-local = tid/6, e = tid%6
    unsigned long long anyb = __ballot(m != 0ull);
    if ((tid & 63) == 0) wflag[tid >> 6] = (anyb != 0ull) ? 1u : 0u;
    __syncthreads();
    unsigned int any = wflag[0] | wflag[1] | wflag[2] | wflag[3] | wflag[4] | wflag[5];
    if (!any) return;                            // k2 already wrote this tile

    // slow path (never taken on this input): per-n VGPR gather.
    // word e: bit j -> input channel j*6 + e   [matches k2's layout]
    size_t obase = (size_t)(t * 16 + b) * 384;
    float pi = pinv_[tid], po = poff_[tid], bb = bp[tid];
    for (int nl = 0; nl < 64; ++nl) {
        float acc = 0.f;
        #pragma unroll
        for (int u = 0; u < 6; ++u) {
            unsigned long long mm = mbase[nl * 6 + u];
            while (mm) {
                int j = __builtin_ctzll(mm);
                mm &= mm - 1;
                int row = j * 6 + u;
                acc += wpT[(size_t)row * 384 + tid];
            }
        }
        out[(obase + tid) * 1024 + g * 64 + nl] = (acc + bb) * pi + po;
    }
}

extern "C" void kernel_launch(void* const* d_in, const int* in_sizes, int n_in,
                              void* d_out, int out_size, void* d_ws, size_t ws_size,
                              hipStream_t stream) {
    const float* x  = (const float*)d_in[0];
    const unsigned char* ak = (const unsigned char*)d_in[1];
    const unsigned char* av = (const unsigned char*)d_in[2];
    const float* wq = (const float*)d_in[3];
    const float* qg = (const float*)d_in[4];
    const float* qb = (const float*)d_in[5];
    const float* qm = (const float*)d_in[6];
    const float* qv = (const float*)d_in[7];
    const float* wp = (const float*)d_in[8];
    const float* bp = (const float*)d_in[9];
    const float* pg = (const float*)d_in[10];
    const float* pb = (const float*)d_in[11];
    const float* pm = (const float*)d_in[12];
    const float* pv = (const float*)d_in[13];
    char* ws = (char*)d_ws;
    float* out = (float*)d_out;

    hipLaunchKernelGGL(k0_prep, dim3(1155), dim3(256), 0, stream,
                       wq, wp, qg, qb, qm, qv, pg, pb, pm, pv, bp, ws);
    hipLaunchKernelGGL(k1_lif, dim3(24576), dim3(256), 0, stream,
                       x, (unsigned long long*)(ws + XM_OFF));
    hipLaunchKernelGGL(k1bc, dim3(256), dim3(256), 0, stream,
                       (const unsigned long long*)(ws + XM_OFF),
                       (unsigned long long*)(ws + XMT_OFF),
                       (unsigned short*)(ws + LISTS2_OFF),
                       (unsigned char*)(ws + LCNT2_OFF));
    hipLaunchKernelGGL(k2_qpath, dim3(1024), dim3(512), 0, stream,
                       (const char*)(ws + WQB_OFF),
                       (const float*)(ws + QINV_OFF), (const float*)(ws + QOFF_OFF),
                       (const unsigned short*)(ws + LISTS2_OFF),
                       (const unsigned char*)(ws + LCNT2_OFF),
                       (const unsigned long long*)(ws + XMT_OFF), ak, av,
                       (const float*)(ws + C0_OFF),
                       (unsigned long long*)(ws + MST_OFF), out);
    hipLaunchKernelGGL(k3_proj, dim3(1024), dim3(384), 0, stream,
                       (const float*)(ws + WPT_OFF), (const float*)(ws + PINV_OFF),
                       (const float*)(ws + POFF_OFF), bp,
                       (const unsigned long long*)(ws + MST_OFF), out);
}

// Round 15
// 101.189 us; speedup vs baseline: 1.1131x; 1.1131x over previous
//
#include <hip/hip_runtime.h>
#include <cstdint>

#define CN (384*1024)          // 393216
#define BCN (16*CN)            // 6291456
#define EPS 1e-5f

typedef float f32x2 __attribute__((ext_vector_type(2)));
typedef float f32x4 __attribute__((ext_vector_type(4)));

// workspace layout (bytes)
#define WPT_OFF   0u           // f32[384][384] = 589824
#define WQB_OFF   589824u      // bf16-as-u16[385][384] (row 384 = zeros), ends 885504
#define QINV_OFF  1179648u
#define QOFF_OFF  (QINV_OFF + 1536u)
#define PINV_OFF  (QINV_OFF + 3072u)
#define POFF_OFF  (QINV_OFF + 4608u)
#define C0_OFF    (QINV_OFF + 6144u)
#define LCNT2_OFF 1187840u     // u8[1024 blocks][64 units], ends 1253376
#define XM_OFF    1310720u     // u64[4][16][16][384] n-packed spikes, ends 4456448
#define XMT_OFF   4456448u     // u64[4][16][1024][6] c-packed spikes, ends 7602176
#define LISTS2_OFF 7602176u    // u16[1024][64][24] offsets (idx*3), ends ~10748032
#define MST_OFF   XM_OFF       // masked q-spikes u64[col][6]; reuses xm (dead after k1bc)

// ---------------- K01: fused {shortcut LIF -> bitmasks} + {weight prep + consts} ---
// blocks [0, 24576): k1 LIF work; blocks [24576, 25731): k0 prep work (independent).
__global__ __launch_bounds__(256) void k01_lif_prep(const float* __restrict__ x,
                                                    const float* __restrict__ wq,
                                                    const float* __restrict__ wp,
                                                    const float* __restrict__ qg,
                                                    const float* __restrict__ qb,
                                                    const float* __restrict__ qm,
                                                    const float* __restrict__ qv,
                                                    const float* __restrict__ pg,
                                                    const float* __restrict__ pb,
                                                    const float* __restrict__ pm,
                                                    const float* __restrict__ pv,
                                                    const float* __restrict__ bp,
                                                    unsigned long long* __restrict__ xm,
                                                    char* __restrict__ ws) {
    if (blockIdx.x < 24576) {
        int wid  = (blockIdx.x * 256 + threadIdx.x) >> 6;   // 0..98303
        int lane = threadIdx.x & 63;
        int c = wid % 384;
        int g = (wid / 384) & 15;
        int b = wid / (384 * 16);
        const float* xp = x + (size_t)b * CN + (size_t)c * 1024 + g * 64 + lane;
        float v = 0.f;
        #pragma unroll
        for (int t = 0; t < 4; ++t) {
            float xv = xp[(size_t)t * BCN];
            float h = v + (xv - v) * 0.5f;                  // v + (x - v)/tau, tau = 2
            bool s = (h >= 1.0f);
            unsigned long long m = __ballot(s);
            v = s ? 0.f : h;
            if (lane == 0) xm[(((size_t)t * 16 + b) * 16 + g) * 384 + c] = m;
        }
        return;
    }
    int bid = blockIdx.x - 24576;                    // 0..1154
    if (bid < 576) {
        int i = bid * 256 + threadIdx.x;             // 0..147455
        int c = i / 384, o = i % 384;
        ((float*)(ws + WPT_OFF))[c * 384 + o] = wp[o * 384 + c];
    } else if (bid < 1154) {
        int j = (bid - 576) * 256 + threadIdx.x;     // 0..147967
        if (j >= 147840) return;                     // 385*384
        int r = j / 384, o = j % 384;
        unsigned short v = 0;
        if (r < 384) {
            unsigned u = __float_as_uint(wq[o * 384 + r]);
            v = (unsigned short)((u + 0x7fffu + ((u >> 16) & 1u)) >> 16);  // rne bf16
        }
        ((unsigned short*)(ws + WQB_OFF))[j] = v;
    } else {
        for (int i = threadIdx.x; i < 384; i += 256) {
            float qi = qg[i] / sqrtf(qv[i] + EPS);
            ((float*)(ws + QINV_OFF))[i] = qi;
            ((float*)(ws + QOFF_OFF))[i] = qb[i] - qm[i] * qi;
            float pi = pg[i] / sqrtf(pv[i] + EPS);
            float po = pb[i] - pm[i] * pi;
            ((float*)(ws + PINV_OFF))[i] = pi;
            ((float*)(ws + POFF_OFF))[i] = po;
            ((float*)(ws + C0_OFF))[i] = bp[i] * pi + po;  // output when GEMM2 input == 0
        }
    }
}

// ---------------- K1bc: fused bit-transpose + offset-list build --------------------
// wave = (t,b,g). 6 x {load 64 row-words, 64 ballots} -> lane n holds its column's
// 6 c-packed words in registers; writes xmT (fallback path) and builds the padded
// u16 offset list + lcnt directly (no intermediate global round-trip).
__global__ __launch_bounds__(256) void k1bc(const unsigned long long* __restrict__ xm,
                                            unsigned long long* __restrict__ xmT,
                                            unsigned short* __restrict__ lists2,
                                            unsigned char* __restrict__ lcnt2) {
    int wid  = (blockIdx.x * 256 + threadIdx.x) >> 6;   // 0..1023 = tb*16+g
    int lane = threadIdx.x & 63;
    int g  = wid & 15;
    int tb = wid >> 4;                                  // t*16 + b
    unsigned long long T[6];
    #pragma unroll
    for (int cg = 0; cg < 6; ++cg) {
        unsigned long long W = xm[((size_t)tb * 16 + g) * 384 + cg * 64 + lane];
        unsigned long long colw = 0ull;
        #pragma unroll
        for (int k = 0; k < 64; ++k) {
            unsigned long long bk = __ballot((W >> k) & 1ull);
            if (lane == k) colw = bk;
        }
        T[cg] = colw;
    }
    const int n   = g * 64 + lane;
    const size_t col = ((size_t)tb << 10) + n;
    #pragma unroll
    for (int cg = 0; cg < 6; ++cg) xmT[col * 6 + cg] = T[cg];
    const int blockid = (tb & 15) * 64 + (n >> 4);      // b*64 + n/16
    const int un = (lane & 15) * 4 + (tb >> 4);         // (n%16)*4 + t
    unsigned short* lp = lists2 + ((size_t)blockid * 64 + un) * 24;
    int k = 0;
    #pragma unroll
    for (int cg = 0; cg < 6; ++cg) {
        unsigned long long m = T[cg];
        while (m) {
            int j = __builtin_ctzll(m);
            m &= m - 1;
            if (k < 24) lp[k] = (unsigned short)((cg * 64 + j) * 3);
            ++k;
        }
    }
    int kk = k > 24 ? 24 : k;
    for (int i = kk; i < 24; ++i) lp[i] = 1152;         // 384*3 -> zero row (always pad)
    lcnt2[(size_t)blockid * 64 + un] =
        (k > 24) ? 0xFF : (unsigned char)((k + 7) >> 3);
}

// ---------------- K2: optimistic write + wave-per-row gather GEMM1 + BN + LIF ------
// block = (b, nt16), 512 threads = 8 waves; wave w owns n-locals {2w, 2w+1}.
// FIRST: unconditionally write out[t,b,:,16n] = c0[o] (no dependency -> the 100MB
// write drains under the whole gather; tiles with spikes are rewritten by k3).
// THEN: one dwordx3 loads a whole 768B bf16 row (lane owns o = lane*6+e); gather,
// BN+LIF+attn-mask, emit msT words consumed by k3's guard.
#define BLO(w) __uint_as_float((w) << 16)
#define BHI(w) __uint_as_float((w) & 0xFFFF0000u)
#define PK(w)  ((f32x2){BLO(w), BHI(w)})
#define RL(v, l) ((unsigned)__builtin_amdgcn_readlane((int)(v), (l)))

#define GROW8(W0, W1, W2, W3) do {                                                \
    uint3 d0_ = *(const uint3*)(wqc + ((size_t)((W0) & 0xffffu) << 8) + voff);    \
    uint3 d1_ = *(const uint3*)(wqc + ((size_t)((W0) >> 16) << 8) + voff);        \
    uint3 d2_ = *(const uint3*)(wqc + ((size_t)((W1) & 0xffffu) << 8) + voff);    \
    uint3 d3_ = *(const uint3*)(wqc + ((size_t)((W1) >> 16) << 8) + voff);        \
    uint3 d4_ = *(const uint3*)(wqc + ((size_t)((W2) & 0xffffu) << 8) + voff);    \
    uint3 d5_ = *(const uint3*)(wqc + ((size_t)((W2) >> 16) << 8) + voff);        \
    uint3 d6_ = *(const uint3*)(wqc + ((size_t)((W3) & 0xffffu) << 8) + voff);    \
    uint3 d7_ = *(const uint3*)(wqc + ((size_t)((W3) >> 16) << 8) + voff);        \
    s0 += ((PK(d0_.x) + PK(d1_.x)) + (PK(d2_.x) + PK(d3_.x)))                     \
        + ((PK(d4_.x) + PK(d5_.x)) + (PK(d6_.x) + PK(d7_.x)));                    \
    s1 += ((PK(d0_.y) + PK(d1_.y)) + (PK(d2_.y) + PK(d3_.y)))                     \
        + ((PK(d4_.y) + PK(d5_.y)) + (PK(d6_.y) + PK(d7_.y)));                    \
    s2 += ((PK(d0_.z) + PK(d1_.z)) + (PK(d2_.z) + PK(d3_.z)))                     \
        + ((PK(d4_.z) + PK(d5_.z)) + (PK(d6_.z) + PK(d7_.z)));                    \
} while (0)

__global__ __launch_bounds__(512, 2) void k2_qpath(const char* __restrict__ wqc,
                                                   const float* __restrict__ qinv_,
                                                   const float* __restrict__ qoff_,
                                                   const unsigned short* __restrict__ lists2,
                                                   const unsigned char* __restrict__ lcnt2,
                                                   const unsigned long long* __restrict__ xmT,
                                                   const unsigned char* __restrict__ ak,
                                                   const unsigned char* __restrict__ av,
                                                   const float* __restrict__ c0,
                                                   unsigned long long* __restrict__ msT,
                                                   float* __restrict__ out) {
    const int tid  = threadIdx.x;
    const int lane = tid & 63;
    const int w    = tid >> 6;                   // wave 0..7
    const int nt   = blockIdx.x & 63;
    const int b    = blockIdx.x >> 6;
    const int voff = lane * 12;                  // 12B per lane: o = lane*6 + e

    // lane-cache the block's gather metadata: lane u holds unit u's 24 u16 offsets
    const char* lb = (const char*)lists2 + (size_t)blockIdx.x * 3072 + lane * 48;
    const uint4 L0 = *(const uint4*)lb;           // slots 0-7
    const uint4 L1 = *(const uint4*)(lb + 16);    // slots 8-15
    const uint4 L2 = *(const uint4*)(lb + 32);    // slots 16-23
    const unsigned lcv = *(const unsigned*)((const char*)lcnt2
                          + (size_t)blockIdx.x * 64 + (lane & 15) * 4);

    // ---- optimistic constant write (no dependency; drains under the gather) ----
    // tile = 384 o x 16 n floats = 1536 float4 units = 3 x 512 threads.
    {
        float cv[3];
        #pragma unroll
        for (int k = 0; k < 3; ++k) cv[k] = c0[(tid + k * 512) >> 2];
        #pragma unroll
        for (int t = 0; t < 4; ++t) {
            f32x4* base4 = (f32x4*)out + (size_t)(t * 16 + b) * 384 * 256 + nt * 4;
            #pragma unroll
            for (int k = 0; k < 3; ++k) {
                int i2 = tid + k * 512;                 // 0..1535
                int o = i2 >> 2, n4 = i2 & 3;           // o in [0,384), n4 in [0,4)
                float vv = cv[k];
                __builtin_nontemporal_store((f32x4){vv, vv, vv, vv},
                                            base4 + (size_t)o * 256 + n4);
            }
        }
    }

    float qi[6], qo[6];
    #pragma unroll
    for (int e = 0; e < 6; ++e) {
        qi[e] = qinv_[lane * 6 + e];
        qo[e] = qoff_[lane * 6 + e];
    }

    #pragma unroll
    for (int i = 0; i < 2; ++i) {
        const int nl = w * 2 + i;                // n-local 0..15 (wave-uniform)
        const int n  = nt * 16 + nl;
        const unsigned lcw = RL(lcv, nl);        // 4 round-counts (one per t)
        f32x2 a0[4], a1[4], a2[4];
        // ---- phase 1: fixed 16 slots per t (compiler-scheduled batches) ----
        #pragma unroll
        for (int t = 0; t < 4; ++t) {
            const int un = nl * 4 + t;           // wave-uniform unit index
            const unsigned Wa = RL(L0.x, un), Wb = RL(L0.y, un);
            const unsigned Wc = RL(L0.z, un), Wd = RL(L0.w, un);
            const unsigned We = RL(L1.x, un), Wf = RL(L1.y, un);
            const unsigned Wg = RL(L1.z, un), Wh = RL(L1.w, un);
            f32x2 s0 = {0.f, 0.f}, s1 = {0.f, 0.f}, s2 = {0.f, 0.f};
            GROW8(Wa, Wb, Wc, Wd);
            GROW8(We, Wf, Wg, Wh);
            a0[t] = s0; a1[t] = s1; a2[t] = s2;
        }
        // ---- phase 2: rare third round (k = 17..24) ----
        #pragma unroll
        for (int t = 0; t < 4; ++t) {
            if (((lcw >> (8 * t)) & 0xffu) == 3u) {
                const int un = nl * 4 + t;
                const unsigned Wa = RL(L2.x, un), Wb = RL(L2.y, un);
                const unsigned Wc = RL(L2.z, un), Wd = RL(L2.w, un);
                f32x2 s0 = a0[t], s1 = a1[t], s2 = a2[t];
                GROW8(Wa, Wb, Wc, Wd);
                a0[t] = s0; a1[t] = s1; a2[t] = s2;
            }
        }
        // ---- phase 3: overflow fallback (k > 24, ~never), recompute from zero ----
        #pragma unroll
        for (int t = 0; t < 4; ++t) {
            if (((lcw >> (8 * t)) & 0xffu) == 0xffu) {
                const int col = ((t * 16 + b) << 10) + n;
                const unsigned long long* mp = xmT + (size_t)col * 6;
                f32x2 s0 = {0.f, 0.f}, s1 = {0.f, 0.f}, s2 = {0.f, 0.f};
                #pragma unroll
                for (int cg = 0; cg < 6; ++cg) {
                    unsigned long long mm = mp[cg];
                    while (mm) {
                        int j = __builtin_ctzll(mm);
                        mm &= mm - 1;
                        uint3 dd = *(const uint3*)(wqc + (size_t)(cg * 64 + j) * 768 + voff);
                        s0 += PK(dd.x); s1 += PK(dd.y); s2 += PK(dd.z);
                    }
                }
                a0[t] = s0; a1[t] = s1; a2[t] = s2;
            }
        }
        // ---- BN + LIF + attn-mask epilogue (6 owned o's per lane) ----
        float v[6] = {0.f, 0.f, 0.f, 0.f, 0.f, 0.f};
        #pragma unroll
        for (int t = 0; t < 4; ++t) {
            const int col = ((t * 16 + b) << 10) + n;
            const float val[6] = {a0[t].x, a0[t].y, a1[t].x, a1[t].y, a2[t].x, a2[t].y};
            bool sp[6];
            #pragma unroll
            for (int e = 0; e < 6; ++e) {
                float q = val[e] * qi[e] + qo[e];
                float h = 0.5f * (v[e] + q);     // v + (q - v)/2
                bool s = (h >= 1.0f);
                v[e] = s ? 0.f : h;
                if (s) {                          // rare: attn lookup only on q-spike
                    size_t ix = ((size_t)((t * 16 + b) * 384 + lane * 6 + e) << 10) + n;
                    s = (ak[ix] != 0) && (av[ix] != 0);
                }
                sp[e] = s;
            }
            unsigned long long B0 = __ballot(sp[0]);
            unsigned long long B1 = __ballot(sp[1]);
            unsigned long long B2 = __ballot(sp[2]);
            unsigned long long B3 = __ballot(sp[3]);
            unsigned long long B4 = __ballot(sp[4]);
            unsigned long long B5 = __ballot(sp[5]);
            // word e: bit l -> o = l*6 + e
            unsigned long long sel = lane == 0 ? B0 : lane == 1 ? B1 : lane == 2 ? B2
                                   : lane == 3 ? B3 : lane == 4 ? B4 : B5;
            if (lane < 6) msT[(size_t)col * 6 + lane] = sel;
        }
    }
}

// ---------------- K3: slow-path guard (gather GEMM2 only where spikes exist) -------
__global__ __launch_bounds__(384) void k3_proj(const float* __restrict__ wpT,
                                               const float* __restrict__ pinv_,
                                               const float* __restrict__ poff_,
                                               const float* __restrict__ bp,
                                               const unsigned long long* __restrict__ msT,
                                               float* __restrict__ out) {
    __shared__ unsigned int wflag[6];
    const int tid = threadIdx.x;
    const int bid = blockIdx.x;
    const int g = bid & 15, b = (bid >> 4) & 15, t = bid >> 8;
    const unsigned long long* mbase = msT + ((size_t)(t * 16 + b) * 1024 + g * 64) * 6;
    unsigned long long m = mbase[tid];           // 384 words: n-local = tid/6, e = tid%6
    unsigned long long anyb = __ballot(m != 0ull);
    if ((tid & 63) == 0) wflag[tid >> 6] = (anyb != 0ull) ? 1u : 0u;
    __syncthreads();
    unsigned int any = wflag[0] | wflag[1] | wflag[2] | wflag[3] | wflag[4] | wflag[5];
    if (!any) return;                            // k2's optimistic write already correct

    // slow path (never taken on this input): per-n VGPR gather.
    // word e: bit j -> input channel j*6 + e   [matches k2's layout]
    size_t obase = (size_t)(t * 16 + b) * 384;
    float pi = pinv_[tid], po = poff_[tid], bb = bp[tid];
    for (int nl = 0; nl < 64; ++nl) {
        float acc = 0.f;
        #pragma unroll
        for (int u = 0; u < 6; ++u) {
            unsigned long long mm = mbase[nl * 6 + u];
            while (mm) {
                int j = __builtin_ctzll(mm);
                mm &= mm - 1;
                int row = j * 6 + u;
                acc += wpT[(size_t)row * 384 + tid];
            }
        }
        out[(obase + tid) * 1024 + g * 64 + nl] = (acc + bb) * pi + po;
    }
}

extern "C" void kernel_launch(void* const* d_in, const int* in_sizes, int n_in,
                              void* d_out, int out_size, void* d_ws, size_t ws_size,
                              hipStream_t stream) {
    const float* x  = (const float*)d_in[0];
    const unsigned char* ak = (const unsigned char*)d_in[1];
    const unsigned char* av = (const unsigned char*)d_in[2];
    const float* wq = (const float*)d_in[3];
    const float* qg = (const float*)d_in[4];
    const float* qb = (const float*)d_in[5];
    const float* qm = (const float*)d_in[6];
    const float* qv = (const float*)d_in[7];
    const float* wp = (const float*)d_in[8];
    const float* bp = (const float*)d_in[9];
    const float* pg = (const float*)d_in[10];
    const float* pb = (const float*)d_in[11];
    const float* pm = (const float*)d_in[12];
    const float* pv = (const float*)d_in[13];
    char* ws = (char*)d_ws;
    float* out = (float*)d_out;

    hipLaunchKernelGGL(k01_lif_prep, dim3(25731), dim3(256), 0, stream,
                       x, wq, wp, qg, qb, qm, qv, pg, pb, pm, pv, bp,
                       (unsigned long long*)(ws + XM_OFF), ws);
    hipLaunchKernelGGL(k1bc, dim3(256), dim3(256), 0, stream,
                       (const unsigned long long*)(ws + XM_OFF),
                       (unsigned long long*)(ws + XMT_OFF),
                       (unsigned short*)(ws + LISTS2_OFF),
                       (unsigned char*)(ws + LCNT2_OFF));
    hipLaunchKernelGGL(k2_qpath, dim3(1024), dim3(512), 0, stream,
                       (const char*)(ws + WQB_OFF),
                       (const float*)(ws + QINV_OFF), (const float*)(ws + QOFF_OFF),
                       (const unsigned short*)(ws + LISTS2_OFF),
                       (const unsigned char*)(ws + LCNT2_OFF),
                       (const unsigned long long*)(ws + XMT_OFF), ak, av,
                       (const float*)(ws + C0_OFF),
                       (unsigned long long*)(ws + MST_OFF), out);
    hipLaunchKernelGGL(k3_proj, dim3(1024), dim3(384), 0, stream,
                       (const float*)(ws + WPT_OFF), (const float*)(ws + PINV_OFF),
                       (const float*)(ws + POFF_OFF), bp,
                       (const unsigned long long*)(ws + MST_OFF), out);
}

// Round 16
// 98.896 us; speedup vs baseline: 1.1389x; 1.0232x over previous
//
#include <hip/hip_runtime.h>
#include <cstdint>

#define CN (384*1024)          // 393216
#define BCN (16*CN)            // 6291456
#define EPS 1e-5f

typedef float f32x2 __attribute__((ext_vector_type(2)));
typedef float f32x4 __attribute__((ext_vector_type(4)));

// workspace layout (bytes)
#define WPT_OFF   0u           // f32[384][384] = 589824
#define WQB_OFF   589824u      // bf16-as-u16[385][384] (row 384 = zeros), ends 885504
#define QINV_OFF  1179648u
#define QOFF_OFF  (QINV_OFF + 1536u)
#define PINV_OFF  (QINV_OFF + 3072u)
#define POFF_OFF  (QINV_OFF + 4608u)
#define C0_OFF    (QINV_OFF + 6144u)
#define LCNT2_OFF 1187840u     // u8[1024 blocks][64 units], ends 1253376
#define XM_OFF    1310720u     // u64[4][16][16][384] n-packed spikes, ends 4456448
#define XMT_OFF   4456448u     // u64[4][16][1024][6] c-packed spikes, ends 7602176
#define LISTS2_OFF 7602176u    // u16[1024][64][24] offsets (idx*3), ends ~10748032
#define MST_OFF   XM_OFF       // masked q-spikes u64[col][6]; reuses xm (dead after k1bc)

// ---------------- K01: fused {shortcut LIF -> bitmasks} + {weight prep + consts} ---
// blocks [0, 24576): k1 LIF work; blocks [24576, 25731): k0 prep work (independent).
__global__ __launch_bounds__(256) void k01_lif_prep(const float* __restrict__ x,
                                                    const float* __restrict__ wq,
                                                    const float* __restrict__ wp,
                                                    const float* __restrict__ qg,
                                                    const float* __restrict__ qb,
                                                    const float* __restrict__ qm,
                                                    const float* __restrict__ qv,
                                                    const float* __restrict__ pg,
                                                    const float* __restrict__ pb,
                                                    const float* __restrict__ pm,
                                                    const float* __restrict__ pv,
                                                    const float* __restrict__ bp,
                                                    unsigned long long* __restrict__ xm,
                                                    char* __restrict__ ws) {
    if (blockIdx.x < 24576) {
        int wid  = (blockIdx.x * 256 + threadIdx.x) >> 6;   // 0..98303
        int lane = threadIdx.x & 63;
        int c = wid % 384;
        int g = (wid / 384) & 15;
        int b = wid / (384 * 16);
        const float* xp = x + (size_t)b * CN + (size_t)c * 1024 + g * 64 + lane;
        float v = 0.f;
        #pragma unroll
        for (int t = 0; t < 4; ++t) {
            float xv = xp[(size_t)t * BCN];
            float h = v + (xv - v) * 0.5f;                  // v + (x - v)/tau, tau = 2
            bool s = (h >= 1.0f);
            unsigned long long m = __ballot(s);
            v = s ? 0.f : h;
            if (lane == 0) xm[(((size_t)t * 16 + b) * 16 + g) * 384 + c] = m;
        }
        return;
    }
    int bid = blockIdx.x - 24576;                    // 0..1154
    if (bid < 576) {
        int i = bid * 256 + threadIdx.x;             // 0..147455
        int c = i / 384, o = i % 384;
        ((float*)(ws + WPT_OFF))[c * 384 + o] = wp[o * 384 + c];
    } else if (bid < 1154) {
        int j = (bid - 576) * 256 + threadIdx.x;     // 0..147967
        if (j >= 147840) return;                     // 385*384
        int r = j / 384, o = j % 384;
        unsigned short v = 0;
        if (r < 384) {
            unsigned u = __float_as_uint(wq[o * 384 + r]);
            v = (unsigned short)((u + 0x7fffu + ((u >> 16) & 1u)) >> 16);  // rne bf16
        }
        ((unsigned short*)(ws + WQB_OFF))[j] = v;
    } else {
        for (int i = threadIdx.x; i < 384; i += 256) {
            float qi = qg[i] / sqrtf(qv[i] + EPS);
            ((float*)(ws + QINV_OFF))[i] = qi;
            ((float*)(ws + QOFF_OFF))[i] = qb[i] - qm[i] * qi;
            float pi = pg[i] / sqrtf(pv[i] + EPS);
            float po = pb[i] - pm[i] * pi;
            ((float*)(ws + PINV_OFF))[i] = pi;
            ((float*)(ws + POFF_OFF))[i] = po;
            ((float*)(ws + C0_OFF))[i] = bp[i] * pi + po;  // output when GEMM2 input == 0
        }
    }
}

// ---------------- K1bc: fused bit-transpose + offset-list build --------------------
// wave = (t,b,g). 6 x {load 64 row-words, 64 ballots} -> lane n holds its column's
// 6 c-packed words in registers; writes xmT (fallback path) and builds the padded
// u16 offset list + lcnt directly (no intermediate global round-trip).
__global__ __launch_bounds__(256) void k1bc(const unsigned long long* __restrict__ xm,
                                            unsigned long long* __restrict__ xmT,
                                            unsigned short* __restrict__ lists2,
                                            unsigned char* __restrict__ lcnt2) {
    int wid  = (blockIdx.x * 256 + threadIdx.x) >> 6;   // 0..1023 = tb*16+g
    int lane = threadIdx.x & 63;
    int g  = wid & 15;
    int tb = wid >> 4;                                  // t*16 + b
    unsigned long long T[6];
    #pragma unroll
    for (int cg = 0; cg < 6; ++cg) {
        unsigned long long W = xm[((size_t)tb * 16 + g) * 384 + cg * 64 + lane];
        unsigned long long colw = 0ull;
        #pragma unroll
        for (int k = 0; k < 64; ++k) {
            unsigned long long bk = __ballot((W >> k) & 1ull);
            if (lane == k) colw = bk;
        }
        T[cg] = colw;
    }
    const int n   = g * 64 + lane;
    const size_t col = ((size_t)tb << 10) + n;
    #pragma unroll
    for (int cg = 0; cg < 6; ++cg) xmT[col * 6 + cg] = T[cg];
    const int blockid = (tb & 15) * 64 + (n >> 4);      // b*64 + n/16
    const int un = (lane & 15) * 4 + (tb >> 4);         // (n%16)*4 + t
    unsigned short* lp = lists2 + ((size_t)blockid * 64 + un) * 24;
    int k = 0;
    #pragma unroll
    for (int cg = 0; cg < 6; ++cg) {
        unsigned long long m = T[cg];
        while (m) {
            int j = __builtin_ctzll(m);
            m &= m - 1;
            if (k < 24) lp[k] = (unsigned short)((cg * 64 + j) * 3);
            ++k;
        }
    }
    int kk = k > 24 ? 24 : k;
    for (int i = kk; i < 24; ++i) lp[i] = 1152;         // 384*3 -> zero row (always pad)
    lcnt2[(size_t)blockid * 64 + un] =
        (k > 24) ? 0xFF : (unsigned char)((k + 7) >> 3);
}

// ---------------- K2: wave-per-row gather GEMM1 + BN + LIF + tail OUTPUT WRITE -----
// block = (b, nt16), 512 threads = 8 waves; wave w owns n-locals {2w, 2w+1}.
// Gather FIRST (vmcnt FIFO stays store-free -> load waits are tight), epilogue,
// THEN the unconditional constant write out[t,b,:,16n] = c0[o] issues last and
// drains under other waves / successor blocks. Spiked tiles rewritten by k3.
#define BLO(w) __uint_as_float((w) << 16)
#define BHI(w) __uint_as_float((w) & 0xFFFF0000u)
#define PK(w)  ((f32x2){BLO(w), BHI(w)})
#define RL(v, l) ((unsigned)__builtin_amdgcn_readlane((int)(v), (l)))

#define GROW8(W0, W1, W2, W3) do {                                                \
    uint3 d0_ = *(const uint3*)(wqc + ((size_t)((W0) & 0xffffu) << 8) + voff);    \
    uint3 d1_ = *(const uint3*)(wqc + ((size_t)((W0) >> 16) << 8) + voff);        \
    uint3 d2_ = *(const uint3*)(wqc + ((size_t)((W1) & 0xffffu) << 8) + voff);    \
    uint3 d3_ = *(const uint3*)(wqc + ((size_t)((W1) >> 16) << 8) + voff);        \
    uint3 d4_ = *(const uint3*)(wqc + ((size_t)((W2) & 0xffffu) << 8) + voff);    \
    uint3 d5_ = *(const uint3*)(wqc + ((size_t)((W2) >> 16) << 8) + voff);        \
    uint3 d6_ = *(const uint3*)(wqc + ((size_t)((W3) & 0xffffu) << 8) + voff);    \
    uint3 d7_ = *(const uint3*)(wqc + ((size_t)((W3) >> 16) << 8) + voff);        \
    s0 += ((PK(d0_.x) + PK(d1_.x)) + (PK(d2_.x) + PK(d3_.x)))                     \
        + ((PK(d4_.x) + PK(d5_.x)) + (PK(d6_.x) + PK(d7_.x)));                    \
    s1 += ((PK(d0_.y) + PK(d1_.y)) + (PK(d2_.y) + PK(d3_.y)))                     \
        + ((PK(d4_.y) + PK(d5_.y)) + (PK(d6_.y) + PK(d7_.y)));                    \
    s2 += ((PK(d0_.z) + PK(d1_.z)) + (PK(d2_.z) + PK(d3_.z)))                     \
        + ((PK(d4_.z) + PK(d5_.z)) + (PK(d6_.z) + PK(d7_.z)));                    \
} while (0)

__global__ __launch_bounds__(512, 2) void k2_qpath(const char* __restrict__ wqc,
                                                   const float* __restrict__ qinv_,
                                                   const float* __restrict__ qoff_,
                                                   const unsigned short* __restrict__ lists2,
                                                   const unsigned char* __restrict__ lcnt2,
                                                   const unsigned long long* __restrict__ xmT,
                                                   const unsigned char* __restrict__ ak,
                                                   const unsigned char* __restrict__ av,
                                                   const float* __restrict__ c0,
                                                   unsigned long long* __restrict__ msT,
                                                   float* __restrict__ out) {
    const int tid  = threadIdx.x;
    const int lane = tid & 63;
    const int w    = tid >> 6;                   // wave 0..7
    const int nt   = blockIdx.x & 63;
    const int b    = blockIdx.x >> 6;
    const int voff = lane * 12;                  // 12B per lane: o = lane*6 + e

    // lane-cache the block's gather metadata: lane u holds unit u's 24 u16 offsets
    const char* lb = (const char*)lists2 + (size_t)blockIdx.x * 3072 + lane * 48;
    const uint4 L0 = *(const uint4*)lb;           // slots 0-7
    const uint4 L1 = *(const uint4*)(lb + 16);    // slots 8-15
    const uint4 L2 = *(const uint4*)(lb + 32);    // slots 16-23
    const unsigned lcv = *(const unsigned*)((const char*)lcnt2
                          + (size_t)blockIdx.x * 64 + (lane & 15) * 4);

    float qi[6], qo[6];
    #pragma unroll
    for (int e = 0; e < 6; ++e) {
        qi[e] = qinv_[lane * 6 + e];
        qo[e] = qoff_[lane * 6 + e];
    }

    #pragma unroll
    for (int i = 0; i < 2; ++i) {
        const int nl = w * 2 + i;                // n-local 0..15 (wave-uniform)
        const int n  = nt * 16 + nl;
        const unsigned lcw = RL(lcv, nl);        // 4 round-counts (one per t)
        f32x2 a0[4], a1[4], a2[4];
        // ---- phase 1: fixed 16 slots per t (compiler-scheduled batches) ----
        #pragma unroll
        for (int t = 0; t < 4; ++t) {
            const int un = nl * 4 + t;           // wave-uniform unit index
            const unsigned Wa = RL(L0.x, un), Wb = RL(L0.y, un);
            const unsigned Wc = RL(L0.z, un), Wd = RL(L0.w, un);
            const unsigned We = RL(L1.x, un), Wf = RL(L1.y, un);
            const unsigned Wg = RL(L1.z, un), Wh = RL(L1.w, un);
            f32x2 s0 = {0.f, 0.f}, s1 = {0.f, 0.f}, s2 = {0.f, 0.f};
            GROW8(Wa, Wb, Wc, Wd);
            GROW8(We, Wf, Wg, Wh);
            a0[t] = s0; a1[t] = s1; a2[t] = s2;
        }
        // ---- phase 2: rare third round (k = 17..24) ----
        #pragma unroll
        for (int t = 0; t < 4; ++t) {
            if (((lcw >> (8 * t)) & 0xffu) == 3u) {
                const int un = nl * 4 + t;
                const unsigned Wa = RL(L2.x, un), Wb = RL(L2.y, un);
                const unsigned Wc = RL(L2.z, un), Wd = RL(L2.w, un);
                f32x2 s0 = a0[t], s1 = a1[t], s2 = a2[t];
                GROW8(Wa, Wb, Wc, Wd);
                a0[t] = s0; a1[t] = s1; a2[t] = s2;
            }
        }
        // ---- phase 3: overflow fallback (k > 24, ~never), recompute from zero ----
        #pragma unroll
        for (int t = 0; t < 4; ++t) {
            if (((lcw >> (8 * t)) & 0xffu) == 0xffu) {
                const int col = ((t * 16 + b) << 10) + n;
                const unsigned long long* mp = xmT + (size_t)col * 6;
                f32x2 s0 = {0.f, 0.f}, s1 = {0.f, 0.f}, s2 = {0.f, 0.f};
                #pragma unroll
                for (int cg = 0; cg < 6; ++cg) {
                    unsigned long long mm = mp[cg];
                    while (mm) {
                        int j = __builtin_ctzll(mm);
                        mm &= mm - 1;
                        uint3 dd = *(const uint3*)(wqc + (size_t)(cg * 64 + j) * 768 + voff);
                        s0 += PK(dd.x); s1 += PK(dd.y); s2 += PK(dd.z);
                    }
                }
                a0[t] = s0; a1[t] = s1; a2[t] = s2;
            }
        }
        // ---- BN + LIF + attn-mask epilogue (6 owned o's per lane) ----
        float v[6] = {0.f, 0.f, 0.f, 0.f, 0.f, 0.f};
        #pragma unroll
        for (int t = 0; t < 4; ++t) {
            const int col = ((t * 16 + b) << 10) + n;
            const float val[6] = {a0[t].x, a0[t].y, a1[t].x, a1[t].y, a2[t].x, a2[t].y};
            bool sp[6];
            #pragma unroll
            for (int e = 0; e < 6; ++e) {
                float q = val[e] * qi[e] + qo[e];
                float h = 0.5f * (v[e] + q);     // v + (q - v)/2
                bool s = (h >= 1.0f);
                v[e] = s ? 0.f : h;
                if (s) {                          // rare: attn lookup only on q-spike
                    size_t ix = ((size_t)((t * 16 + b) * 384 + lane * 6 + e) << 10) + n;
                    s = (ak[ix] != 0) && (av[ix] != 0);
                }
                sp[e] = s;
            }
            unsigned long long B0 = __ballot(sp[0]);
            unsigned long long B1 = __ballot(sp[1]);
            unsigned long long B2 = __ballot(sp[2]);
            unsigned long long B3 = __ballot(sp[3]);
            unsigned long long B4 = __ballot(sp[4]);
            unsigned long long B5 = __ballot(sp[5]);
            // word e: bit l -> o = l*6 + e
            unsigned long long sel = lane == 0 ? B0 : lane == 1 ? B1 : lane == 2 ? B2
                                   : lane == 3 ? B3 : lane == 4 ? B4 : B5;
            if (lane < 6) msT[(size_t)col * 6 + lane] = sel;
        }
    }

    // ---- tail optimistic constant write (issues after ALL loads; drains async) ----
    // tile = 384 o x 16 n floats = 1536 float4 units = 3 x 512 threads.
    {
        float cv[3];
        #pragma unroll
        for (int k = 0; k < 3; ++k) cv[k] = c0[(tid + k * 512) >> 2];
        #pragma unroll
        for (int t = 0; t < 4; ++t) {
            f32x4* base4 = (f32x4*)out + (size_t)(t * 16 + b) * 384 * 256 + nt * 4;
            #pragma unroll
            for (int k = 0; k < 3; ++k) {
                int i2 = tid + k * 512;                 // 0..1535
                int o = i2 >> 2, n4 = i2 & 3;           // o in [0,384), n4 in [0,4)
                float vv = cv[k];
                __builtin_nontemporal_store((f32x4){vv, vv, vv, vv},
                                            base4 + (size_t)o * 256 + n4);
            }
        }
    }
}

// ---------------- K3: slow-path guard (gather GEMM2 only where spikes exist) -------
__global__ __launch_bounds__(384) void k3_proj(const float* __restrict__ wpT,
                                               const float* __restrict__ pinv_,
                                               const float* __restrict__ poff_,
                                               const float* __restrict__ bp,
                                               const unsigned long long* __restrict__ msT,
                                               float* __restrict__ out) {
    __shared__ unsigned int wflag[6];
    const int tid = threadIdx.x;
    const int bid = blockIdx.x;
    const int g = bid & 15, b = (bid >> 4) & 15, t = bid >> 8;
    const unsigned long long* mbase = msT + ((size_t)(t * 16 + b) * 1024 + g * 64) * 6;
    unsigned long long m = mbase[tid];           // 384 words: n-local = tid/6, e = tid%6
    unsigned long long anyb = __ballot(m != 0ull);
    if ((tid & 63) == 0) wflag[tid >> 6] = (anyb != 0ull) ? 1u : 0u;
    __syncthreads();
    unsigned int any = wflag[0] | wflag[1] | wflag[2] | wflag[3] | wflag[4] | wflag[5];
    if (!any) return;                            // k2's optimistic write already correct

    // slow path (never taken on this input): per-n VGPR gather.
    // word e: bit j -> input channel j*6 + e   [matches k2's layout]
    size_t obase = (size_t)(t * 16 + b) * 384;
    float pi = pinv_[tid], po = poff_[tid], bb = bp[tid];
    for (int nl = 0; nl < 64; ++nl) {
        float acc = 0.f;
        #pragma unroll
        for (int u = 0; u < 6; ++u) {
            unsigned long long mm = mbase[nl * 6 + u];
            while (mm) {
                int j = __builtin_ctzll(mm);
                mm &= mm - 1;
                int row = j * 6 + u;
                acc += wpT[(size_t)row * 384 + tid];
            }
        }
        out[(obase + tid) * 1024 + g * 64 + nl] = (acc + bb) * pi + po;
    }
}

extern "C" void kernel_launch(void* const* d_in, const int* in_sizes, int n_in,
                              void* d_out, int out_size, void* d_ws, size_t ws_size,
                              hipStream_t stream) {
    const float* x  = (const float*)d_in[0];
    const unsigned char* ak = (const unsigned char*)d_in[1];
    const unsigned char* av = (const unsigned char*)d_in[2];
    const float* wq = (const float*)d_in[3];
    const float* qg = (const float*)d_in[4];
    const float* qb = (const float*)d_in[5];
    const float* qm = (const float*)d_in[6];
    const float* qv = (const float*)d_in[7];
    const float* wp = (const float*)d_in[8];
    const float* bp = (const float*)d_in[9];
    const float* pg = (const float*)d_in[10];
    const float* pb = (const float*)d_in[11];
    const float* pm = (const float*)d_in[12];
    const float* pv = (const float*)d_in[13];
    char* ws = (char*)d_ws;
    float* out = (float*)d_out;

    hipLaunchKernelGGL(k01_lif_prep, dim3(25731), dim3(256), 0, stream,
                       x, wq, wp, qg, qb, qm, qv, pg, pb, pm, pv, bp,
                       (unsigned long long*)(ws + XM_OFF), ws);
    hipLaunchKernelGGL(k1bc, dim3(256), dim3(256), 0, stream,
                       (const unsigned long long*)(ws + XM_OFF),
                       (unsigned long long*)(ws + XMT_OFF),
                       (unsigned short*)(ws + LISTS2_OFF),
                       (unsigned char*)(ws + LCNT2_OFF));
    hipLaunchKernelGGL(k2_qpath, dim3(1024), dim3(512), 0, stream,
                       (const char*)(ws + WQB_OFF),
                       (const float*)(ws + QINV_OFF), (const float*)(ws + QOFF_OFF),
                       (const unsigned short*)(ws + LISTS2_OFF),
                       (const unsigned char*)(ws + LCNT2_OFF),
                       (const unsigned long long*)(ws + XMT_OFF), ak, av,
                       (const float*)(ws + C0_OFF),
                       (unsigned long long*)(ws + MST_OFF), out);
    hipLaunchKernelGGL(k3_proj, dim3(1024), dim3(384), 0, stream,
                       (const float*)(ws + WPT_OFF), (const float*)(ws + PINV_OFF),
                       (const float*)(ws + POFF_OFF), bp,
                       (const unsigned long long*)(ws + MST_OFF), out);
}